// Round 11
// baseline (393663.281 us; speedup 1.0000x reference)
//
#include <hip/hip_runtime.h>
#include <hip/hip_fp16.h>
#include <hip/hip_cooperative_groups.h>

namespace cg = cooperative_groups;

#define H      2048
#define NIN    512
#define TH     (3 * H)
#define SEQLEN 2048
#define KSP    204          // int(2048 * 0.1)
#define NBLK   256
#define NTHR_S 1024         // split kernel: 16 waves/block
#define NTHR_F 512          // fallback kernel

typedef unsigned int uint32;

// ---------- packed fp16 weight segments in d_ws (same layout as R8) ----------
// per segment: [elem j][row r][u = kk*2+p2][lane] (uint32 = 2 fp16)
// cols per uint: c0 = 256*kk + 4*lane + 2*p2 -> (c0, c0+1)
constexpr long O_EA = 0;                       // enc Wih0  (xdim 512,  NU=4)
constexpr long O_EB = O_EA + 1572864;          // enc Whh0  (xdim 2048, NU=16)
constexpr long O_EC = O_EB + 6291456;          // enc Wih1
constexpr long O_ED = O_EC + 6291456;          // enc Whh1
constexpr long O_DA = O_ED + 6291456;          // dec Wih0
constexpr long O_DB = O_DA + 1572864;          // dec Whh0
constexpr long O_DC = O_DB + 6291456;          // dec Wih1
constexpr long O_DD = O_DC + 6291456;          // dec Whh1
constexpr long O_WO = O_DD + 6291456;          // Wout (512 rows, NU=16)
constexpr long U_TOTAL = O_WO + 524288;        // 158 MiB
constexpr size_t WS_STATE_BYTES = 65536;

__device__ __forceinline__ float wave_reduce_f(float v) {
#pragma unroll
    for (int m = 32; m >= 1; m >>= 1) v += __shfl_xor(v, m, 64);
    return v;
}
__device__ __forceinline__ float sigmoidf_(float v) { return 1.f / (1.f + expf(-v)); }
__device__ __forceinline__ float2 h2f(uint32 u) {
    __half2 h = *reinterpret_cast<__half2*>(&u);
    return __half22float2(h);
}
__device__ __forceinline__ float rfl(float x) {
    return __uint_as_float(__builtin_amdgcn_readfirstlane(__float_as_uint(x)));
}

// ---------- fp32 -> packed fp16 prep ----------
__global__ void pack_kernel(const float* __restrict__ src, uint32* __restrict__ dst,
                            int total, int xdim, int nrows)
{
    int KK = xdim / 256;
    for (int i = blockIdx.x * blockDim.x + threadIdx.x; i < total;
         i += gridDim.x * blockDim.x) {
        int l = i & 63;
        int rest = i >> 6;
        int p2 = rest & 1; rest >>= 1;
        int kk = rest % KK; rest /= KK;
        int r  = rest % nrows; rest /= nrows;
        int j  = rest;
        int c0 = 256 * kk + 4 * l + 2 * p2;
        const float* row = src + ((size_t)r * H + j) * xdim;
        unsigned short b0 = __half_as_ushort(__float2half_rn(row[c0]));
        unsigned short b1 = __half_as_ushort(__float2half_rn(row[c0 + 1]));
        dst[i] = ((uint32)b1 << 16) | b0;
    }
}

// ---------- union weight block: 96 uint32, compile-time indexed ----------
// G0: wa rows r at [r*4+u] (0..11), wb at [12 + r*16+u] (12..59), wo at [60..75]
// G1: wc at [r*16+u] (0..47), wd at [48 + r*16+u] (48..95)
template <int BASE, int NU>
__device__ __forceinline__ void loadw(uint32 (&w)[96], const uint32* __restrict__ seg,
                                      int j, int lane)
{
#pragma unroll
    for (int r = 0; r < 3; ++r)
#pragma unroll
        for (int u = 0; u < NU; ++u)
            w[BASE + r * NU + u] = seg[((size_t)(j * 3 + r) * NU + u) * 64 + lane];
}
__device__ __forceinline__ void loadwo(uint32 (&w)[96], const uint32* __restrict__ seg,
                                       int j, int lane)
{
#pragma unroll
    for (int u = 0; u < 16; ++u)
        w[60 + u] = seg[((size_t)j * 16 + u) * 64 + lane];
}

template <int BASE, int NU>
__device__ __forceinline__ void dot3(const uint32 (&w)[96],
                                     const float* __restrict__ vec, int lane,
                                     float acc[3])
{
#pragma unroll
    for (int kk = 0; kk < NU / 2; ++kk) {
        float4 v = ((const float4*)vec)[kk * 64 + lane];
#pragma unroll
        for (int r = 0; r < 3; ++r) {
            float2 lo = h2f(w[BASE + r * NU + 2 * kk]);
            float2 hi = h2f(w[BASE + r * NU + 2 * kk + 1]);
            acc[r] = fmaf(lo.x, v.x, acc[r]); acc[r] = fmaf(lo.y, v.y, acc[r]);
            acc[r] = fmaf(hi.x, v.z, acc[r]); acc[r] = fmaf(hi.y, v.w, acc[r]);
        }
    }
}

// GRU cell: input-proj rows at <BI,NI>, h-proj rows at <BI+3*NI, 16>.
template <int BI, int NI>
__device__ __forceinline__ float cellu(const uint32 (&w)[96], int j, int lane,
    const float* __restrict__ x, const float* __restrict__ h,
    float bir, float biz, float bin, float bhr, float bhz, float bhn)
{
    float gi[3] = {0.f, 0.f, 0.f};
    dot3<BI, NI>(w, x, lane, gi);
    float gh[3] = {0.f, 0.f, 0.f};
    dot3<BI + 3 * NI, 16>(w, h, lane, gh);
    float hj  = h[j];
    float sr  = wave_reduce_f(gi[0] + gh[0]);
    float sz  = wave_reduce_f(gi[1] + gh[1]);
    float sn  = wave_reduce_f(gi[2]);
    float shn = wave_reduce_f(gh[2]);
    float r = sigmoidf_(sr + bir + bhr);
    float z = sigmoidf_(sz + biz + bhz);
    float n = tanhf(sn + bin + r * (shn + bhn));
    return (1.f - z) * n + z * hj;
}

// ---------- persistent split kernel: G0 waves own layer0 (+Wout), G1 own layer1 ----------
__global__ void __launch_bounds__(NTHR_S, 4)
seqae_split_kernel(const float* __restrict__ seq,
                   const uint32* __restrict__ U,
                   const float* __restrict__ ebih, const float* __restrict__ ebhh,
                   const float* __restrict__ dbih, const float* __restrict__ dbhh,
                   const float* __restrict__ dbout,
                   float* __restrict__ out,
                   float* __restrict__ wsf)
{
    cg::grid_group grid = cg::this_grid();
    const int lane = threadIdx.x & 63;
    const int wv   = threadIdx.x >> 6;          // 0..15
    const bool g1  = (wv >= 8);
    const int j    = blockIdx.x * 8 + (wv & 7); // 0..2047 within each group

    float* loss = wsf;
    float* h0b[2] = { wsf + 64, wsf + 64 + H };
    float* h1b[2] = { wsf + 64 + 2 * H, wsf + 64 + 3 * H };

    {   // init (ws poisoned 0xAA each call)
        int gtid = blockIdx.x * NTHR_S + threadIdx.x;
        if (gtid == 0) *loss = 0.f;
        for (int i = gtid; i < H; i += NBLK * NTHR_S) { h0b[0][i] = 0.f; h1b[0][i] = 0.f; }
    }
    grid.sync();

    uint32 wreg[96];
    float b0, b1, b2, b3, b4, b5;   // biases (SGPR via readfirstlane)
    if (!g1) {
        loadw<0, 4>(wreg, U + O_EA, j, lane);
        loadw<12, 16>(wreg, U + O_EB, j, lane);
        b0 = rfl(ebih[j]); b1 = rfl(ebih[H + j]); b2 = rfl(ebih[2 * H + j]);
        b3 = rfl(ebhh[j]); b4 = rfl(ebhh[H + j]); b5 = rfl(ebhh[2 * H + j]);
    } else {
        loadw<0, 16>(wreg, U + O_EC, j, lane);
        loadw<48, 16>(wreg, U + O_ED, j, lane);
        const float* bi = ebih + TH; const float* bh = ebhh + TH;
        b0 = rfl(bi[j]); b1 = rfl(bi[H + j]); b2 = rfl(bi[2 * H + j]);
        b3 = rfl(bh[j]); b4 = rfl(bh[H + j]); b5 = rfl(bh[2 * H + j]);
    }

    int c0 = 0, c1 = 0;

    // ---- encoder: phase ph runs layer0(t=ph) on G0 CONCURRENTLY with layer1(t=ph-1) on G1
    for (int ph = 0; ph <= SEQLEN; ++ph) {
        if (!g1) {
            if (ph < SEQLEN) {
                float v = cellu<0, 4>(wreg, j, lane, seq + (size_t)ph * NIN, h0b[c0],
                                      b0, b1, b2, b3, b4, b5);
                if (lane == 0) h0b[c0 ^ 1][j] = v;
            }
        } else {
            if (ph >= 1) {
                float v = cellu<0, 16>(wreg, j, lane, h0b[c0], h1b[c1],
                                       b0, b1, b2, b3, b4, b5);
                if (lane == 0) h1b[c1 ^ 1][j] = v;
            }
        }
        grid.sync();
        if (ph < SEQLEN) c0 ^= 1;
        if (ph >= 1)     c1 ^= 1;
    }

    // ---- exact top-k (k=204) on final h1 (G0 waves), lax.top_k tie-break ----
    {
        const float* hs = h1b[c1];
        if (!g1) {
            float vj = hs[j];
            int cnt = 0;
            for (int i = lane; i < H; i += 64) {
                float vi = hs[i];
                cnt += (vi > vj) || (vi == vj && i < j);
            }
#pragma unroll
            for (int m = 32; m >= 1; m >>= 1) cnt += __shfl_xor(cnt, m, 64);
            if (lane == 0) h1b[c1 ^ 1][j] = (cnt < KSP) ? vj : 0.f;
        }
        grid.sync();
        c1 ^= 1;
    }

    // ---- decoder weights (reuse the same register block) ----
    float boutj = 0.f;
    if (!g1) {
        loadw<0, 4>(wreg, U + O_DA, j, lane);
        loadw<12, 16>(wreg, U + O_DB, j, lane);
        if (j < NIN) { loadwo(wreg, U + O_WO, j, lane); boutj = rfl(dbout[j]); }
        b0 = rfl(dbih[j]); b1 = rfl(dbih[H + j]); b2 = rfl(dbih[2 * H + j]);
        b3 = rfl(dbhh[j]); b4 = rfl(dbhh[H + j]); b5 = rfl(dbhh[2 * H + j]);
    } else {
        loadw<0, 16>(wreg, U + O_DC, j, lane);
        loadw<48, 16>(wreg, U + O_DD, j, lane);
        const float* bi = dbih + TH; const float* bh = dbhh + TH;
        b0 = rfl(bi[j]); b1 = rfl(bi[H + j]); b2 = rfl(bi[2 * H + j]);
        b3 = rfl(bh[j]); b4 = rfl(bh[H + j]); b5 = rfl(bh[2 * H + j]);
    }

    // ---- decoder: 2047 steps x 3 phases ----
    float lsum = 0.f;
    for (int t = 0; t < SEQLEN - 1; ++t) {
        if (!g1) {
            const float* x = (t == 0) ? (seq + (size_t)(SEQLEN - 1) * NIN)
                                      : (out + (size_t)(t - 1) * NIN);
            float v = cellu<0, 4>(wreg, j, lane, x, h0b[c0], b0, b1, b2, b3, b4, b5);
            if (lane == 0) h0b[c0 ^ 1][j] = v;
        }
        grid.sync(); c0 ^= 1;

        if (g1) {
            float v = cellu<0, 16>(wreg, j, lane, h0b[c0], h1b[c1], b0, b1, b2, b3, b4, b5);
            if (lane == 0) h1b[c1 ^ 1][j] = v;
        }
        grid.sync(); c1 ^= 1;

        if (!g1 && j < NIN) {
            const float* h1n = h1b[c1];
            float a = 0.f;
#pragma unroll
            for (int kk = 0; kk < 8; ++kk) {
                float4 v = ((const float4*)h1n)[kk * 64 + lane];
                float2 lo = h2f(wreg[60 + 2 * kk]);
                float2 hi = h2f(wreg[60 + 2 * kk + 1]);
                a = fmaf(lo.x, v.x, a); a = fmaf(lo.y, v.y, a);
                a = fmaf(hi.x, v.z, a); a = fmaf(hi.y, v.w, a);
            }
            a = wave_reduce_f(a);
            float o = a + boutj;
            if (lane == 0) out[(size_t)t * NIN + j] = o;
            float tg = seq[(size_t)(SEQLEN - 2 - t) * NIN + j];
            float d = o - tg;
            lsum = fmaf(d, d, lsum);
        }
        grid.sync();
    }

    if (!g1 && j < NIN && lane == 0) atomicAdd(loss, lsum);
    grid.sync();
    if (blockIdx.x == 0 && threadIdx.x == 0)
        out[(size_t)(SEQLEN - 1) * NIN] = (*loss) * (1.f / ((float)NIN * (float)SEQLEN));
}

// ======================================================================
// Fallback (Round-6 kernel, fp32 streaming) — used if ws_size too small.
// ======================================================================
struct Params {
    const float* seq;
    const float* eWih0; const float* eWih1; const float* eWhh;
    const float* ebih;  const float* ebhh;
    const float* dWih0; const float* dWih1; const float* dWhh;
    const float* dbih;  const float* dbhh;
    const float* dWout; const float* dbout;
    float* out;
    float* ws;
};

template <int XDIM>
__device__ __forceinline__ void gru_phase_fb(int j, int lane,
    const float* __restrict__ Wih, const float* __restrict__ Whh,
    const float* __restrict__ bih, const float* __restrict__ bhh,
    const float* __restrict__ x,
    const float* __restrict__ hcur, float* __restrict__ hnxt)
{
    const float4* wir = (const float4*)(Wih + (size_t)j * XDIM);
    const float4* wiz = (const float4*)(Wih + (size_t)(H + j) * XDIM);
    const float4* win = (const float4*)(Wih + (size_t)(2 * H + j) * XDIM);
    const float4* whr = (const float4*)(Whh + (size_t)j * H);
    const float4* whz = (const float4*)(Whh + (size_t)(H + j) * H);
    const float4* whn = (const float4*)(Whh + (size_t)(2 * H + j) * H);
    const float4* x4  = (const float4*)x;
    const float4* h4  = (const float4*)hcur;

    float air = 0.f, aiz = 0.f, ain = 0.f;
#pragma unroll
    for (int k = 0; k < XDIM / 256; ++k) {
        int i = lane + 64 * k;
        float4 xv = x4[i];
        float4 a = wir[i], b = wiz[i], c = win[i];
        air = fmaf(a.x, xv.x, air); air = fmaf(a.y, xv.y, air);
        air = fmaf(a.z, xv.z, air); air = fmaf(a.w, xv.w, air);
        aiz = fmaf(b.x, xv.x, aiz); aiz = fmaf(b.y, xv.y, aiz);
        aiz = fmaf(b.z, xv.z, aiz); aiz = fmaf(b.w, xv.w, aiz);
        ain = fmaf(c.x, xv.x, ain); ain = fmaf(c.y, xv.y, ain);
        ain = fmaf(c.z, xv.z, ain); ain = fmaf(c.w, xv.w, ain);
    }
    float ahr = 0.f, ahz = 0.f, ahn = 0.f;
#pragma unroll
    for (int k = 0; k < H / 256; ++k) {
        int i = lane + 64 * k;
        float4 hv = h4[i];
        float4 a = whr[i], b = whz[i], c = whn[i];
        ahr = fmaf(a.x, hv.x, ahr); ahr = fmaf(a.y, hv.y, ahr);
        ahr = fmaf(a.z, hv.z, ahr); ahr = fmaf(a.w, hv.w, ahr);
        ahz = fmaf(b.x, hv.x, ahz); ahz = fmaf(b.y, hv.y, ahz);
        ahz = fmaf(b.z, hv.z, ahz); ahz = fmaf(b.w, hv.w, ahz);
        ahn = fmaf(c.x, hv.x, ahn); ahn = fmaf(c.y, hv.y, ahn);
        ahn = fmaf(c.z, hv.z, ahn); ahn = fmaf(c.w, hv.w, ahn);
    }
    float sr   = wave_reduce_f(air + ahr);
    float sz   = wave_reduce_f(aiz + ahz);
    float sin_ = wave_reduce_f(ain);
    float shn  = wave_reduce_f(ahn);

    if (lane == 0) {
        float r = sigmoidf_(sr + bih[j] + bhh[j]);
        float z = sigmoidf_(sz + bih[H + j] + bhh[H + j]);
        float n = tanhf(sin_ + bih[2 * H + j] + r * (shn + bhh[2 * H + j]));
        hnxt[j] = (1.f - z) * n + z * hcur[j];
    }
}

__global__ void __launch_bounds__(NTHR_F)
seqae_fallback_kernel(Params p)
{
    cg::grid_group grid = cg::this_grid();
    const int lane = threadIdx.x & 63;
    const int wid  = blockIdx.x * (NTHR_F / 64) + (threadIdx.x >> 6);

    float* loss = p.ws;
    float* h0a  = p.ws + 64;
    float* h0b  = h0a + H;
    float* h1a  = h0b + H;
    float* h1b  = h1a + H;

    {
        int gtid = blockIdx.x * NTHR_F + threadIdx.x;
        if (gtid == 0) *loss = 0.f;
        for (int i = gtid; i < H; i += NBLK * NTHR_F) { h0a[i] = 0.f; h1a[i] = 0.f; }
    }
    grid.sync();

    const float* ebih0 = p.ebih;        const float* ebih1 = p.ebih + TH;
    const float* ebhh0 = p.ebhh;        const float* ebhh1 = p.ebhh + TH;
    const float* eWhh0 = p.eWhh;        const float* eWhh1 = p.eWhh + (size_t)TH * H;

    float* h0c = h0a; float* h0n = h0b;
    float* h1c = h1a; float* h1n = h1b;

    for (int t = 0; t < SEQLEN; ++t) {
        const float* x = p.seq + (size_t)t * NIN;
        gru_phase_fb<NIN>(wid, lane, p.eWih0, eWhh0, ebih0, ebhh0, x, h0c, h0n);
        grid.sync();
        gru_phase_fb<H>(wid, lane, p.eWih1, eWhh1, ebih1, ebhh1, h0n, h1c, h1n);
        grid.sync();
        float* tmp;
        tmp = h0c; h0c = h0n; h0n = tmp;
        tmp = h1c; h1c = h1n; h1n = tmp;
    }

    {
        int jj = wid;
        float vj = h1c[jj];
        int cnt = 0;
        for (int i = lane; i < H; i += 64) {
            float vi = h1c[i];
            cnt += (vi > vj) || (vi == vj && i < jj);
        }
#pragma unroll
        for (int m = 32; m >= 1; m >>= 1) cnt += __shfl_xor(cnt, m, 64);
        if (lane == 0) h1n[jj] = (cnt < KSP) ? vj : 0.f;
    }
    grid.sync();
    { float* tmp = h1c; h1c = h1n; h1n = tmp; }

    const float* dbih0 = p.dbih;        const float* dbih1 = p.dbih + TH;
    const float* dbhh0 = p.dbhh;        const float* dbhh1 = p.dbhh + TH;
    const float* dWhh0 = p.dWhh;        const float* dWhh1 = p.dWhh + (size_t)TH * H;

    float lsum = 0.f;
    for (int t = 0; t < SEQLEN - 1; ++t) {
        const float* x = (t == 0) ? (p.seq + (size_t)(SEQLEN - 1) * NIN)
                                  : (p.out + (size_t)(t - 1) * NIN);
        gru_phase_fb<NIN>(wid, lane, p.dWih0, dWhh0, dbih0, dbhh0, x, h0c, h0n);
        grid.sync();
        gru_phase_fb<H>(wid, lane, p.dWih1, dWhh1, dbih1, dbhh1, h0n, h1c, h1n);
        grid.sync();
        if (wid < NIN) {
            int jj = wid;
            const float4* wo = (const float4*)(p.dWout + (size_t)jj * H);
            const float4* h4 = (const float4*)h1n;
            float a = 0.f;
#pragma unroll
            for (int k = 0; k < H / 256; ++k) {
                int i = lane + 64 * k;
                float4 w = wo[i]; float4 hv = h4[i];
                a = fmaf(w.x, hv.x, a); a = fmaf(w.y, hv.y, a);
                a = fmaf(w.z, hv.z, a); a = fmaf(w.w, hv.w, a);
            }
            a = wave_reduce_f(a);
            if (lane == 0) {
                float o = a + p.dbout[jj];
                p.out[(size_t)t * NIN + jj] = o;
                float tg = p.seq[(size_t)(SEQLEN - 2 - t) * NIN + jj];
                float d = o - tg;
                lsum = fmaf(d, d, lsum);
            }
        }
        grid.sync();
        float* tmp;
        tmp = h0c; h0c = h0n; h0n = tmp;
        tmp = h1c; h1c = h1n; h1n = tmp;
    }

    if (wid < NIN && lane == 0) atomicAdd(loss, lsum);
    grid.sync();
    if (blockIdx.x == 0 && threadIdx.x == 0) {
        p.out[(size_t)(SEQLEN - 1) * NIN] = (*loss) * (1.f / ((float)NIN * (float)SEQLEN));
    }
}

extern "C" void kernel_launch(void* const* d_in, const int* in_sizes, int n_in,
                              void* d_out, int out_size, void* d_ws, size_t ws_size,
                              hipStream_t stream)
{
    const float* seq   = (const float*)d_in[0];
    const float* eWih0 = (const float*)d_in[1];
    const float* eWih1 = (const float*)d_in[2];
    const float* eWhh  = (const float*)d_in[3];
    const float* ebih  = (const float*)d_in[4];
    const float* ebhh  = (const float*)d_in[5];
    const float* dWih0 = (const float*)d_in[6];
    const float* dWih1 = (const float*)d_in[7];
    const float* dWhh  = (const float*)d_in[8];
    const float* dbih  = (const float*)d_in[9];
    const float* dbhh  = (const float*)d_in[10];
    const float* dWout = (const float*)d_in[11];
    const float* dbout = (const float*)d_in[12];
    float* out = (float*)d_out;
    float* wsf = (float*)d_ws;

    size_t need = WS_STATE_BYTES + (size_t)U_TOTAL * 4;
    if (ws_size >= need) {
        uint32* U = (uint32*)((char*)d_ws + WS_STATE_BYTES);
        const int PB = 256, PG = 1024;
        pack_kernel<<<PG, PB, 0, stream>>>(eWih0, U + O_EA, 1572864, NIN, 3);
        pack_kernel<<<PG, PB, 0, stream>>>(eWhh,  U + O_EB, 6291456, H, 3);
        pack_kernel<<<PG, PB, 0, stream>>>(eWih1, U + O_EC, 6291456, H, 3);
        pack_kernel<<<PG, PB, 0, stream>>>(eWhh + (size_t)TH * H, U + O_ED, 6291456, H, 3);
        pack_kernel<<<PG, PB, 0, stream>>>(dWih0, U + O_DA, 1572864, NIN, 3);
        pack_kernel<<<PG, PB, 0, stream>>>(dWhh,  U + O_DB, 6291456, H, 3);
        pack_kernel<<<PG, PB, 0, stream>>>(dWih1, U + O_DC, 6291456, H, 3);
        pack_kernel<<<PG, PB, 0, stream>>>(dWhh + (size_t)TH * H, U + O_DD, 6291456, H, 3);
        pack_kernel<<<PG, PB, 0, stream>>>(dWout, U + O_WO, 524288, H, 1);

        const uint32* Uc = U;
        void* args[] = { &seq, &Uc, &ebih, &ebhh, &dbih, &dbhh, &dbout, &out, &wsf };
        (void)hipLaunchCooperativeKernel((void*)seqae_split_kernel, dim3(NBLK), dim3(NTHR_S),
                                         args, 0, stream);
    } else {
        Params p;
        p.seq = seq; p.eWih0 = eWih0; p.eWih1 = eWih1; p.eWhh = eWhh;
        p.ebih = ebih; p.ebhh = ebhh;
        p.dWih0 = dWih0; p.dWih1 = dWih1; p.dWhh = dWhh;
        p.dbih = dbih; p.dbhh = dbhh;
        p.dWout = dWout; p.dbout = dbout;
        p.out = out; p.ws = wsf;
        void* args[] = { &p };
        (void)hipLaunchCooperativeKernel((void*)seqae_fallback_kernel, dim3(NBLK), dim3(NTHR_F),
                                         args, 0, stream);
    }
}